// Round 1
// baseline (31056.570 us; speedup 1.0000x reference)
//
#include <hip/hip_runtime.h>
#include <hip/hip_cooperative_groups.h>
#include <math.h>

typedef unsigned short u16;
typedef unsigned int   u32;

#define B_ 32
#define S_ 256
#define E_ 256
#define H_ 512
#define L_ 1024
#define G4 2048      // 4*H

// ---- workspace layout (in floats) ----
#define OFF_HEB  0                         // he bf16: 16,777,216 u16 = 8,388,608 floats
#define OFF_WIHB 8388608                   // Wih bf16: 1,572,864 u16 = 786,432 floats
#define OFF_WHHB 9175040                   // Whh bf16: 1,048,576 u16 = 524,288 floats
#define OFF_H    9699328
#define OFF_C    9715712
#define OFF_ATT  9732096
#define OFF_CNT  9748480                   // 128 floats reserved; 96 u32 counters used
#define OFF_PG2  9748608                   // persistent pg: 16*32*2048 = 1,048,576
#define OFF_SE2  10797184                  // 32*512 = 16,384
#define OFF_PA2  10813568                  // 32*8*520 = 133,120  (end 10,946,688)
// legacy (fallback path only; disjoint execution, may overlap PG2 region)
#define OFF_PGL  9748608                   // 8*32*2048 = 524,288
#define OFF_PSEL 10272896                  // 4*32*512  = 65,536
#define OFF_PAL  10338432                  // 32*16*520 = 266,240

namespace cg = cooperative_groups;

__device__ inline u16 f2bf(float x) {
    u32 u = __float_as_uint(x);
    u += 0x7fffu + ((u >> 16) & 1u);
    return (u16)(u >> 16);
}
__device__ inline float bflo(u32 q) { return __uint_as_float(q << 16); }
__device__ inline float bfhi(u32 q) { return __uint_as_float(q & 0xffff0000u); }

// ---------------- zero init for h, c, att, counters ----------------
__global__ void k_zero(float* __restrict__ p, int n) {
    int i = blockIdx.x * blockDim.x + threadIdx.x;
    if (i < n) p[i] = 0.f;
}

// ---------------- one-time: convert W_ih, W_hh to bf16 ----------------
__global__ void k_cvtw(const float* __restrict__ Wih, const float* __restrict__ Whh,
                       u16* __restrict__ wihb, u16* __restrict__ whhb) {
    int i = (blockIdx.x * 256 + threadIdx.x) * 4;
    if (i < 1572864) {
        float4 v = *(const float4*)(Wih + i);
        ushort4 r; r.x = f2bf(v.x); r.y = f2bf(v.y); r.z = f2bf(v.z); r.w = f2bf(v.w);
        *(ushort4*)(wihb + i) = r;
    } else {
        int j = i - 1572864;
        float4 v = *(const float4*)(Whh + j);
        ushort4 r; r.x = f2bf(v.x); r.y = f2bf(v.y); r.z = f2bf(v.z); r.w = f2bf(v.w);
        *(ushort4*)(whhb + j) = r;
    }
}

// ---------------- h_e = encoder_h @ W_h.T + b_h  (bf16 out) ----------------
__global__ __launch_bounds__(256) void k_he(const float* __restrict__ A,
                                            const float* __restrict__ W,
                                            const float* __restrict__ bias,
                                            u16* __restrict__ C) {
    __shared__ float As[64][36];
    __shared__ float Bs[64][37];
    const int m0 = blockIdx.y * 64;
    const int n0 = blockIdx.x * 64;
    const int tid = threadIdx.x;
    const int tx = tid & 15, ty = tid >> 4;
    float acc[4][4] = {};
    for (int kk = 0; kk < 512; kk += 32) {
        #pragma unroll
        for (int i = 0; i < 2; ++i) {
            int idx = tid + i * 256;
            int r = idx >> 3, c4 = (idx & 7) << 2;
            float4 va = *(const float4*)(A + (size_t)(m0 + r) * 512 + kk + c4);
            *(float4*)&As[r][c4] = va;
            float4 vb = *(const float4*)(W + (size_t)(n0 + r) * 512 + kk + c4);
            Bs[r][c4 + 0] = vb.x; Bs[r][c4 + 1] = vb.y;
            Bs[r][c4 + 2] = vb.z; Bs[r][c4 + 3] = vb.w;
        }
        __syncthreads();
        #pragma unroll
        for (int k2 = 0; k2 < 32; ++k2) {
            float a[4], b[4];
            #pragma unroll
            for (int i = 0; i < 4; ++i) a[i] = As[ty * 4 + i][k2];
            #pragma unroll
            for (int j = 0; j < 4; ++j) b[j] = Bs[tx * 4 + j][k2];
            #pragma unroll
            for (int i = 0; i < 4; ++i)
                #pragma unroll
                for (int j = 0; j < 4; ++j) acc[i][j] += a[i] * b[j];
        }
        __syncthreads();
    }
    float bj[4];
    #pragma unroll
    for (int j = 0; j < 4; ++j) bj[j] = bias[n0 + tx * 4 + j];
    #pragma unroll
    for (int i = 0; i < 4; ++i) {
        ushort4 r4;
        r4.x = f2bf(acc[i][0] + bj[0]); r4.y = f2bf(acc[i][1] + bj[1]);
        r4.z = f2bf(acc[i][2] + bj[2]); r4.w = f2bf(acc[i][3] + bj[3]);
        *(ushort4*)(C + (size_t)(m0 + ty * 4 + i) * 512 + n0 + tx * 4) = r4;
    }
}

// ==================== persistent cooperative kernel ====================

struct PArgs {
    const float* y;
    const float* bih;
    const float* bhh;
    const float* Wsm;   // W_s fp32 [512][512]
    const float* bs;
    const u16*   heb;
    const u16*   wihb;
    const u16*   whhb;
    float* h;
    float* c;
    float* att;
    float* pg;          // [16][32][2048]
    float* se;          // [32][512]
    float* pa;          // [32][8][520]
    u32*   cnt;         // [0..31]=h, [32..63]=se, [64..95]=pa
    float* out_h;
    float* out_att;
};

struct SMem {
    u16 he[128][520];                 // resident h_e tile (pad 520: full-BW b128 reads)
    union {
        struct {
            u16   wst[40][132];       // W k-major: wst[k][row]; pad 132 -> 8B-aligned rows
            float xs[32][44];         // x[b][k] fp32
        } p1;
        struct {
            float gsum[4][64];
            float hb[512];
            float part[64][9];
            float seb[512];
            float epart[128][5];
            float pl[128];
            float red[2];
            float redz[2];
            float mz[2];
            int   islast;
            float ctxp[2][512];
        } p2;
    } u;
};

__global__ __launch_bounds__(512) void k_persist(PArgs a) {
    cg::grid_group grid = cg::this_grid();
    __shared__ SMem sm;
    const int bk  = blockIdx.x;       // 0..255
    const int tid = threadIdx.x;      // 0..511

    // roles
    const int b_at = bk >> 3, ch = bk & 7;     // P2: batch, l-chunk (128 l each)
    const int rt = bk >> 4, kc = bk & 15;      // P1: 32-d row tile, 80-k chunk
    const int rr = tid & 31, bb = tid >> 5;    // P1: 4 rows, 2 batches per thread
    const int b0 = bb * 2;

    // ---- load resident h_e tile: he[b_at][ch*128 + l][:] ----
    {
        const u16* src = a.heb + ((size_t)(b_at * L_ + ch * 128)) * H_;
        #pragma unroll
        for (int i = 0; i < 16; ++i) {
            int s = tid + i * 512;            // 8192 uint4 slots
            int l = s >> 6, v = s & 63;
            *(uint4*)&sm.he[l][v * 8] = *(const uint4*)(src + (size_t)l * H_ + v * 8);
        }
    }
    __syncthreads();

    for (int t = 0; t < S_; ++t) {
        // ================= P1: gates partials =================
        float acc[4][2] = {};
        #pragma unroll
        for (int sub = 0; sub < 2; ++sub) {
            const int kbase = kc * 80 + sub * 40;
            // stage W chunk (k-major scatter, bf16)
            for (int s = tid; s < 640; s += 512) {
                int lr = s / 5, v = s - lr * 5;
                int w  = ((lr >> 5) << 9) + rt * 32 + (lr & 31);
                int kg = kbase + v * 8;
                const u16* wp = (kg < 768) ? (a.wihb + (size_t)w * 768 + kg)
                                           : (a.whhb + (size_t)w * 512 + (kg - 768));
                uint4 q = *(const uint4*)wp;
                int kb = v * 8;
                sm.u.p1.wst[kb + 0][lr] = (u16)(q.x);
                sm.u.p1.wst[kb + 1][lr] = (u16)(q.x >> 16);
                sm.u.p1.wst[kb + 2][lr] = (u16)(q.y);
                sm.u.p1.wst[kb + 3][lr] = (u16)(q.y >> 16);
                sm.u.p1.wst[kb + 4][lr] = (u16)(q.z);
                sm.u.p1.wst[kb + 5][lr] = (u16)(q.z >> 16);
                sm.u.p1.wst[kb + 6][lr] = (u16)(q.w);
                sm.u.p1.wst[kb + 7][lr] = (u16)(q.w >> 16);
            }
            // stage x chunk: x = [y_t | att | h]
            for (int s = tid; s < 320; s += 512) {
                int b = s / 10, v = s - b * 10;
                int kg = kbase + v * 4;
                float4 xv;
                if (kg < 256)      xv = *(const float4*)(a.y + (size_t)b * (S_ * E_) + (size_t)t * E_ + kg);
                else if (kg < 768) xv = *(const float4*)(a.att + b * H_ + (kg - 256));
                else               xv = *(const float4*)(a.h + b * H_ + (kg - 768));
                *(float4*)&sm.u.p1.xs[b][v * 4] = xv;
            }
            __syncthreads();
            {
                const float* xr0 = sm.u.p1.xs[b0];
                const float* xr1 = sm.u.p1.xs[b0 + 1];
                #pragma unroll
                for (int k4 = 0; k4 < 10; ++k4) {
                    float4 x0 = *(const float4*)(xr0 + k4 * 4);
                    float4 x1 = *(const float4*)(xr1 + k4 * 4);
                    #pragma unroll
                    for (int kk = 0; kk < 4; ++kk) {
                        uint2 q = *(const uint2*)&sm.u.p1.wst[k4 * 4 + kk][rr * 4];
                        float w0 = bflo(q.x), w1 = bfhi(q.x);
                        float w2 = bflo(q.y), w3 = bfhi(q.y);
                        float xa = (kk == 0) ? x0.x : (kk == 1) ? x0.y : (kk == 2) ? x0.z : x0.w;
                        float xb = (kk == 0) ? x1.x : (kk == 1) ? x1.y : (kk == 2) ? x1.z : x1.w;
                        acc[0][0] += w0 * xa; acc[0][1] += w0 * xb;
                        acc[1][0] += w1 * xa; acc[1][1] += w1 * xb;
                        acc[2][0] += w2 * xa; acc[2][1] += w2 * xb;
                        acc[3][0] += w3 * xa; acc[3][1] += w3 * xb;
                    }
                }
            }
            __syncthreads();
        }
        #pragma unroll
        for (int i = 0; i < 4; ++i) {
            int lr = rr * 4 + i;
            int w  = ((lr >> 5) << 9) + rt * 32 + (lr & 31);
            size_t base = (size_t)kc * (B_ * G4) + w;
            a.pg[base + (size_t)b0 * G4]       = acc[i][0];
            a.pg[base + (size_t)(b0 + 1) * G4] = acc[i][1];
        }

        grid.sync();   // S1: gates partials visible

        // ================= P2: lstm -> se -> attn -> comb =================
        // --- A: LSTM pointwise for (b_at, d in [ch*64, ch*64+64)) ---
        if (tid < 256) {
            int d_loc = tid & 63, g = tid >> 6;
            int w = (g << 9) + ch * 64 + d_loc;
            float s = a.bih[w] + a.bhh[w];
            #pragma unroll
            for (int kcs = 0; kcs < 16; ++kcs)
                s += a.pg[(size_t)kcs * (B_ * G4) + (size_t)b_at * G4 + w];
            sm.u.p2.gsum[g][d_loc] = s;
        }
        __syncthreads();
        if (tid < 64) {
            int d   = ch * 64 + tid;
            int idx = b_at * H_ + d;
            float gi = sm.u.p2.gsum[0][tid], gf = sm.u.p2.gsum[1][tid];
            float gg = sm.u.p2.gsum[2][tid], go = sm.u.p2.gsum[3][tid];
            float si = 1.f / (1.f + expf(-gi));
            float sf = 1.f / (1.f + expf(-gf));
            float so = 1.f / (1.f + expf(-go));
            float cc = sf * a.c[idx] + si * tanhf(gg);
            float hh = so * tanhf(cc);
            a.c[idx] = cc;
            a.h[idx] = hh;
            a.out_h[(size_t)b_at * (S_ * H_) + (size_t)t * H_ + d] = hh;
        }
        __syncthreads();
        if (tid == 0) {
            __hip_atomic_fetch_add(&a.cnt[b_at], 1u, __ATOMIC_RELEASE, __HIP_MEMORY_SCOPE_AGENT);
            u32 tgt = 8u * (u32)(t + 1);
            while (__hip_atomic_load(&a.cnt[b_at], __ATOMIC_ACQUIRE, __HIP_MEMORY_SCOPE_AGENT) < tgt) {}
        }
        __syncthreads();

        // --- B: s_e slice rows [ch*64, ch*64+64), fp32 W_s ---
        sm.u.p2.hb[tid] = a.h[b_at * H_ + tid];
        __syncthreads();
        {
            int r_loc = tid >> 3, kq = tid & 7;
            const float* wrow = a.Wsm + (size_t)(ch * 64 + r_loc) * 512;
            float dp = 0.f;
            #pragma unroll
            for (int j = 0; j < 16; ++j) {
                int k = (j * 8 + kq) * 4;
                float4 wv = *(const float4*)(wrow + k);
                dp += wv.x * sm.u.p2.hb[k]     + wv.y * sm.u.p2.hb[k + 1]
                    + wv.z * sm.u.p2.hb[k + 2] + wv.w * sm.u.p2.hb[k + 3];
            }
            sm.u.p2.part[r_loc][kq] = dp;
        }
        __syncthreads();
        if (tid < 64) {
            float v = a.bs[ch * 64 + tid];
            #pragma unroll
            for (int q = 0; q < 8; ++q) v += sm.u.p2.part[tid][q];
            a.se[b_at * H_ + ch * 64 + tid] = v;
        }
        __syncthreads();
        if (tid == 0) {
            __hip_atomic_fetch_add(&a.cnt[32 + b_at], 1u, __ATOMIC_RELEASE, __HIP_MEMORY_SCOPE_AGENT);
            u32 tgt = 8u * (u32)(t + 1);
            while (__hip_atomic_load(&a.cnt[32 + b_at], __ATOMIC_ACQUIRE, __HIP_MEMORY_SCOPE_AGENT) < tgt) {}
        }
        __syncthreads();
        sm.u.p2.seb[tid] = a.se[b_at * H_ + tid];
        __syncthreads();

        // --- C: e-dots over this block's 128 l (h_e from LDS) ---
        {
            int l = tid & 127, kq = tid >> 7;
            const u16*   hr = &sm.he[l][kq * 128];
            const float* sb = &sm.u.p2.seb[kq * 128];
            float dp = 0.f;
            #pragma unroll
            for (int j = 0; j < 16; ++j) {
                uint4 q = *(const uint4*)(hr + j * 8);
                const float* s8 = sb + j * 8;
                dp += s8[0] * bflo(q.x) + s8[1] * bfhi(q.x)
                    + s8[2] * bflo(q.y) + s8[3] * bfhi(q.y)
                    + s8[4] * bflo(q.z) + s8[5] * bfhi(q.z)
                    + s8[6] * bflo(q.w) + s8[7] * bfhi(q.w);
            }
            sm.u.p2.epart[l][kq] = dp;
        }
        __syncthreads();

        // --- D: chunk softmax partial (128 values, waves 0-1) ---
        float ee = 0.f;
        if (tid < 128) {
            ee = sm.u.p2.epart[tid][0] + sm.u.p2.epart[tid][1]
               + sm.u.p2.epart[tid][2] + sm.u.p2.epart[tid][3];
            float m = ee;
            #pragma unroll
            for (int off = 1; off < 64; off <<= 1) m = fmaxf(m, __shfl_xor(m, off));
            if ((tid & 63) == 0) sm.u.p2.red[tid >> 6] = m;
        }
        __syncthreads();
        if (tid < 128) {
            float m = fmaxf(sm.u.p2.red[0], sm.u.p2.red[1]);
            float p = __expf(ee - m);
            sm.u.p2.pl[tid] = p;
            float Z = p;
            #pragma unroll
            for (int off = 1; off < 64; off <<= 1) Z += __shfl_xor(Z, off);
            if ((tid & 63) == 0) sm.u.p2.redz[tid >> 6] = Z;
            if (tid == 0) sm.u.p2.mz[0] = m;
        }
        __syncthreads();

        // --- E: ctx partial (h_e from LDS) ---
        {
            int hp = tid & 255, lh = tid >> 8;
            float a0 = 0.f, a1 = 0.f;
            #pragma unroll 8
            for (int j = 0; j < 64; ++j) {
                int l = lh * 64 + j;
                u32 q = *(const u32*)&sm.he[l][hp * 2];
                float p = sm.u.p2.pl[l];
                a0 += p * bflo(q); a1 += p * bfhi(q);
            }
            sm.u.p2.ctxp[lh][hp * 2]     = a0;
            sm.u.p2.ctxp[lh][hp * 2 + 1] = a1;
        }
        __syncthreads();
        {
            float* dst = a.pa + ((size_t)b_at * 8 + ch) * 520;
            if (tid < 256) {
                float v0 = sm.u.p2.ctxp[0][tid * 2]     + sm.u.p2.ctxp[1][tid * 2];
                float v1 = sm.u.p2.ctxp[0][tid * 2 + 1] + sm.u.p2.ctxp[1][tid * 2 + 1];
                dst[tid * 2]     = v0;
                dst[tid * 2 + 1] = v1;
            }
            if (tid == 0) {
                dst[512] = sm.u.p2.mz[0];
                dst[513] = sm.u.p2.redz[0] + sm.u.p2.redz[1];
            }
        }
        __syncthreads();
        if (tid == 0) {
            u32 old = __hip_atomic_fetch_add(&a.cnt[64 + b_at], 1u, __ATOMIC_ACQ_REL, __HIP_MEMORY_SCOPE_AGENT);
            sm.u.p2.islast = (old == 8u * (u32)(t + 1) - 1u) ? 1 : 0;
        }
        __syncthreads();
        if (sm.u.p2.islast) {
            // --- comb: this block saw all 8 chunk partials for b_at ---
            const float* pab = a.pa + (size_t)b_at * (8 * 520);
            if (tid < 256) {
                float mv[8], zv[8];
                float M = -3.4e38f;
                #pragma unroll
                for (int cc = 0; cc < 8; ++cc) {
                    mv[cc] = pab[cc * 520 + 512];
                    zv[cc] = pab[cc * 520 + 513];
                    M = fmaxf(M, mv[cc]);
                }
                float wv[8], Zt = 0.f;
                #pragma unroll
                for (int cc = 0; cc < 8; ++cc) { wv[cc] = __expf(mv[cc] - M); Zt += wv[cc] * zv[cc]; }
                float inv = 1.f / Zt;
                float a0 = 0.f, a1 = 0.f;
                #pragma unroll
                for (int cc = 0; cc < 8; ++cc) {
                    a0 += wv[cc] * pab[cc * 520 + tid * 2];
                    a1 += wv[cc] * pab[cc * 520 + tid * 2 + 1];
                }
                a0 *= inv; a1 *= inv;
                a.att[b_at * H_ + tid * 2]     = a0;
                a.att[b_at * H_ + tid * 2 + 1] = a1;
                size_t ob = (size_t)b_at * (S_ * H_) + (size_t)t * H_;
                a.out_att[ob + tid * 2]     = a0;
                a.out_att[ob + tid * 2 + 1] = a1;
            }
        }

        grid.sync();   // S2: att + h ready for next step
    }
}

// ==================== legacy fallback kernels (verbatim) ====================

__global__ __launch_bounds__(256) void k_gates(const float* __restrict__ y,
                                               const float* __restrict__ att,
                                               const float* __restrict__ h,
                                               const u16* __restrict__ wihb,
                                               const u16* __restrict__ whhb,
                                               float* __restrict__ pg, int t) {
    __shared__ float xs[32][36];
    __shared__ float Ws[64][36];
    const int tid = threadIdx.x;
    const int r = tid & 63;
    const int b0 = (tid >> 6) * 8;
    const int r0 = blockIdx.x * 64;
    const int kbeg = blockIdx.y * 160;
    float acc[8] = {};
    for (int kk = kbeg; kk < kbeg + 160; kk += 32) {
        {
            int b = tid >> 3, j0 = (tid & 7) << 2;
            float4 v;
            if (kk < 256)      v = *(const float4*)(y + (size_t)b * (S_ * E_) + t * E_ + kk + j0);
            else if (kk < 768) v = *(const float4*)(att + b * H_ + (kk - 256) + j0);
            else               v = *(const float4*)(h + b * H_ + (kk - 768) + j0);
            *(float4*)&xs[b][j0] = v;
        }
        {
            int rr = tid >> 2, c8 = (tid & 3) << 3;
            const u16* wp;
            if (kk < 768) wp = wihb + (size_t)(r0 + rr) * 768 + kk + c8;
            else          wp = whhb + (size_t)(r0 + rr) * 512 + (kk - 768) + c8;
            uint4 q = *(const uint4*)wp;
            Ws[rr][c8 + 0] = bflo(q.x); Ws[rr][c8 + 1] = bfhi(q.x);
            Ws[rr][c8 + 2] = bflo(q.y); Ws[rr][c8 + 3] = bfhi(q.y);
            Ws[rr][c8 + 4] = bflo(q.z); Ws[rr][c8 + 5] = bfhi(q.z);
            Ws[rr][c8 + 6] = bflo(q.w); Ws[rr][c8 + 7] = bfhi(q.w);
        }
        __syncthreads();
        #pragma unroll
        for (int j = 0; j < 32; j += 4) {
            float4 w4 = *(float4*)&Ws[r][j];
            #pragma unroll
            for (int bb = 0; bb < 8; ++bb) {
                float4 x4 = *(float4*)&xs[b0 + bb][j];
                acc[bb] += w4.x * x4.x + w4.y * x4.y + w4.z * x4.z + w4.w * x4.w;
            }
        }
        __syncthreads();
    }
    #pragma unroll
    for (int bb = 0; bb < 8; ++bb)
        pg[(size_t)blockIdx.y * (B_ * G4) + (b0 + bb) * G4 + r0 + r] = acc[bb];
}

__global__ void k_lstm(const float* __restrict__ pg,
                       const float* __restrict__ bih, const float* __restrict__ bhh,
                       float* __restrict__ c, float* __restrict__ h,
                       float* __restrict__ out_h, int t) {
    int idx = blockIdx.x * blockDim.x + threadIdx.x;
    int b = idx >> 9, d = idx & 511;
    float gi = bih[d] + bhh[d];
    float gf = bih[512 + d] + bhh[512 + d];
    float gg = bih[1024 + d] + bhh[1024 + d];
    float go = bih[1536 + d] + bhh[1536 + d];
    #pragma unroll
    for (int s = 0; s < 8; ++s) {
        const float* p = pg + (size_t)s * (B_ * G4) + b * G4;
        gi += p[d]; gf += p[512 + d]; gg += p[1024 + d]; go += p[1536 + d];
    }
    float si = 1.f / (1.f + expf(-gi));
    float sf = 1.f / (1.f + expf(-gf));
    float so = 1.f / (1.f + expf(-go));
    float cc = sf * c[idx] + si * tanhf(gg);
    float hh = so * tanhf(cc);
    c[idx] = cc;
    h[idx] = hh;
    out_h[(size_t)b * (S_ * H_) + t * H_ + d] = hh;
}

__global__ __launch_bounds__(256) void k_se(const float* __restrict__ h,
                                            const float* __restrict__ Ws_,
                                            float* __restrict__ pse) {
    __shared__ float xs[32][36];
    __shared__ float Ws[64][36];
    const int tid = threadIdx.x;
    const int r = tid & 63;
    const int b0 = (tid >> 6) * 8;
    const int r0 = blockIdx.x * 64;
    const int kbeg = blockIdx.y * 128;
    float acc[8] = {};
    for (int kk = kbeg; kk < kbeg + 128; kk += 32) {
        {
            int b = tid >> 3, j0 = (tid & 7) << 2;
            *(float4*)&xs[b][j0] = *(const float4*)(h + b * H_ + kk + j0);
        }
        #pragma unroll
        for (int i = 0; i < 2; ++i) {
            int idx = tid + i * 256;
            int rr = idx >> 3, c4 = (idx & 7) << 2;
            *(float4*)&Ws[rr][c4] = *(const float4*)(Ws_ + (size_t)(r0 + rr) * 512 + kk + c4);
        }
        __syncthreads();
        #pragma unroll
        for (int j = 0; j < 32; j += 4) {
            float4 w4 = *(float4*)&Ws[r][j];
            #pragma unroll
            for (int bb = 0; bb < 8; ++bb) {
                float4 x4 = *(float4*)&xs[b0 + bb][j];
                acc[bb] += w4.x * x4.x + w4.y * x4.y + w4.z * x4.z + w4.w * x4.w;
            }
        }
        __syncthreads();
    }
    #pragma unroll
    for (int bb = 0; bb < 8; ++bb)
        pse[(size_t)blockIdx.y * (B_ * H_) + (b0 + bb) * H_ + r0 + r] = acc[bb];
}

__global__ __launch_bounds__(256) void k_attn(const float* __restrict__ pse,
                                              const float* __restrict__ bs,
                                              const u16* __restrict__ he,
                                              float* __restrict__ pa) {
    __shared__ float se[512];
    __shared__ float part[64][5];
    __shared__ float pl[64];
    __shared__ float mz[2];
    const int b = blockIdx.y;
    const int l0 = blockIdx.x * 64;
    const int t = threadIdx.x;
    #pragma unroll
    for (int i = 0; i < 2; ++i) {
        int hh = t + i * 256;
        float v = bs[hh];
        #pragma unroll
        for (int s = 0; s < 4; ++s) v += pse[(size_t)s * (B_ * H_) + b * H_ + hh];
        se[hh] = v;
    }
    __syncthreads();
    const int l = t & 63, w = t >> 6;
    const u16* hrow = he + ((size_t)b * L_ + l0 + l) * H_ + w * 128;
    const float* sew = &se[w * 128];
    float dp = 0.f;
    #pragma unroll
    for (int kc = 0; kc < 128; kc += 8) {
        uint4 q = *(const uint4*)(hrow + kc);
        dp += sew[kc + 0] * bflo(q.x) + sew[kc + 1] * bfhi(q.x)
            + sew[kc + 2] * bflo(q.y) + sew[kc + 3] * bfhi(q.y)
            + sew[kc + 4] * bflo(q.z) + sew[kc + 5] * bfhi(q.z)
            + sew[kc + 6] * bflo(q.w) + sew[kc + 7] * bfhi(q.w);
    }
    part[l][w] = dp;
    __syncthreads();
    if (t < 64) {
        float e = part[t][0] + part[t][1] + part[t][2] + part[t][3];
        float m = e;
        #pragma unroll
        for (int off = 1; off < 64; off <<= 1) m = fmaxf(m, __shfl_xor(m, off));
        float p = __expf(e - m);
        float Z = p;
        #pragma unroll
        for (int off = 1; off < 64; off <<= 1) Z += __shfl_xor(Z, off);
        pl[t] = p;
        if (t == 0) { mz[0] = m; mz[1] = Z; }
    }
    __syncthreads();
    float a0 = 0.f, a1 = 0.f;
    const u16* base2 = he + ((size_t)b * L_ + l0) * H_ + t * 2;
    #pragma unroll 4
    for (int j = 0; j < 64; ++j) {
        u32 q = *(const u32*)(base2 + (size_t)j * H_);
        float p = pl[j];
        a0 += p * bflo(q); a1 += p * bfhi(q);
    }
    float* dst = pa + ((size_t)b * 16 + blockIdx.x) * 520;
    dst[t * 2] = a0; dst[t * 2 + 1] = a1;
    if (t == 0) { dst[512] = mz[0]; dst[513] = mz[1]; }
}

__global__ __launch_bounds__(256) void k_comb(const float* __restrict__ pa,
                                              float* __restrict__ att,
                                              float* __restrict__ out_att, int t) {
    __shared__ float sm[16], sz[16], swt[16], sZt;
    const int b = blockIdx.x;
    const int tid = threadIdx.x;
    if (tid < 16) {
        sm[tid] = pa[((size_t)b * 16 + tid) * 520 + 512];
        sz[tid] = pa[((size_t)b * 16 + tid) * 520 + 513];
    }
    __syncthreads();
    if (tid == 0) {
        float M = sm[0];
        #pragma unroll
        for (int i = 1; i < 16; ++i) M = fmaxf(M, sm[i]);
        float Zt = 0.f;
        #pragma unroll
        for (int i = 0; i < 16; ++i) { float wv = __expf(sm[i] - M); swt[i] = wv; Zt += wv * sz[i]; }
        sZt = Zt;
    }
    __syncthreads();
    const float inv = 1.f / sZt;
    float a0 = 0.f, a1 = 0.f;
    #pragma unroll
    for (int i = 0; i < 16; ++i) {
        const float* p = pa + ((size_t)b * 16 + i) * 520 + tid * 2;
        float wv = swt[i];
        a0 += wv * p[0]; a1 += wv * p[1];
    }
    a0 *= inv; a1 *= inv;
    att[b * H_ + tid * 2] = a0;
    att[b * H_ + tid * 2 + 1] = a1;
    out_att[(size_t)b * (S_ * H_) + t * H_ + tid * 2] = a0;
    out_att[(size_t)b * (S_ * H_) + t * H_ + tid * 2 + 1] = a1;
}

extern "C" void kernel_launch(void* const* d_in, const int* in_sizes, int n_in,
                              void* d_out, int out_size, void* d_ws, size_t ws_size,
                              hipStream_t stream) {
    const float* y   = (const float*)d_in[0];
    const float* enc = (const float*)d_in[1];
    const float* Wih = (const float*)d_in[2];
    const float* bih = (const float*)d_in[3];
    const float* Whh = (const float*)d_in[4];
    const float* bhh = (const float*)d_in[5];
    const float* Ws_ = (const float*)d_in[6];
    const float* bs  = (const float*)d_in[7];
    const float* Wh  = (const float*)d_in[8];
    const float* bh  = (const float*)d_in[9];

    float* ws    = (float*)d_ws;
    u16*   heb   = (u16*)(ws + OFF_HEB);
    u16*   wihb  = (u16*)(ws + OFF_WIHB);
    u16*   whhb  = (u16*)(ws + OFF_WHHB);
    float* h     = ws + OFF_H;
    float* c     = ws + OFF_C;
    float* att   = ws + OFF_ATT;
    u32*   cnt   = (u32*)(ws + OFF_CNT);
    float* out_h   = (float*)d_out;
    float* out_att = out_h + (size_t)B_ * S_ * H_;

    // zero h, c, att and the 128-float counter region (contiguous)
    k_zero<<<(3 * B_ * H_ + 128 + 255) / 256, 256, 0, stream>>>(h, 3 * B_ * H_ + 128);
    k_cvtw<<<(1572864 + 1048576) / 4 / 256, 256, 0, stream>>>(Wih, Whh, wihb, whhb);
    k_he<<<dim3(H_ / 64, (B_ * L_) / 64), 256, 0, stream>>>(enc, Wh, bh, heb);

    PArgs pargs;
    pargs.y = y; pargs.bih = bih; pargs.bhh = bhh; pargs.Wsm = Ws_; pargs.bs = bs;
    pargs.heb = heb; pargs.wihb = wihb; pargs.whhb = whhb;
    pargs.h = h; pargs.c = c; pargs.att = att;
    pargs.pg = ws + OFF_PG2; pargs.se = ws + OFF_SE2; pargs.pa = ws + OFF_PA2;
    pargs.cnt = cnt; pargs.out_h = out_h; pargs.out_att = out_att;
    void* kp[] = { (void*)&pargs };
    hipError_t err = hipLaunchCooperativeKernel(reinterpret_cast<void*>(k_persist),
                                                dim3(256), dim3(512), kp, 0, stream);
    if (err != hipSuccess) {
        // fallback: legacy 5-kernel per-step loop
        float* pg  = ws + OFF_PGL;
        float* pse = ws + OFF_PSEL;
        float* pa  = ws + OFF_PAL;
        for (int t = 0; t < S_; ++t) {
            k_gates<<<dim3(32, 8), 256, 0, stream>>>(y, att, h, wihb, whhb, pg, t);
            k_lstm<<<(B_ * H_) / 256, 256, 0, stream>>>(pg, bih, bhh, c, h, out_h, t);
            k_se<<<dim3(8, 4), 256, 0, stream>>>(h, Ws_, pse);
            k_attn<<<dim3(16, 32), 256, 0, stream>>>(pse, bs, heb, pa);
            k_comb<<<32, 256, 0, stream>>>(pa, att, out_att, t);
        }
    }
}

// Round 2
// 20708.965 us; speedup vs baseline: 1.4997x; 1.4997x over previous
//
#include <hip/hip_runtime.h>
#include <math.h>

typedef unsigned short u16;
typedef unsigned int   u32;

#define B_ 32
#define S_ 256
#define E_ 256
#define H_ 512
#define L_ 1024
#define G4 2048      // 4*H

// ---- workspace layout (in floats) ----
#define OFF_HEB  0                         // he bf16: 16,777,216 u16 = 8,388,608 floats
#define OFF_WIHB 8388608                   // (fallback only) Wih bf16
#define OFF_WHHB 9175040                   // (fallback only) Whh bf16
#define OFF_H    9699328                   // h double-buffer [2][32][512] (2nd half = old OFF_C)
#define OFF_C    9715712                   // h buffer 1 (coop) / c (fallback)
#define OFF_ATT  9732096
#define OFF_CNT  9748480                   // 128 floats; u32 counters
#define OFF_SE2  10797184                  // 32*512
#define OFF_PA2  10813568                  // 32*8*520
// legacy fallback scratch
#define OFF_PGL  9748608
#define OFF_PSEL 10272896
#define OFF_PAL  10338432

__device__ inline u16 f2bf(float x) {
    u32 u = __float_as_uint(x);
    u += 0x7fffu + ((u >> 16) & 1u);
    return (u16)(u >> 16);
}
__device__ inline float bflo(u32 q) { return __uint_as_float(q << 16); }
__device__ inline float bfhi(u32 q) { return __uint_as_float(q & 0xffff0000u); }

// ---------------- zero init ----------------
__global__ void k_zero(float* __restrict__ p, int n) {
    int i = blockIdx.x * blockDim.x + threadIdx.x;
    if (i < n) p[i] = 0.f;
}

// ---------------- fallback-only: convert W_ih, W_hh to bf16 ----------------
__global__ void k_cvtw(const float* __restrict__ Wih, const float* __restrict__ Whh,
                       u16* __restrict__ wihb, u16* __restrict__ whhb) {
    int i = (blockIdx.x * 256 + threadIdx.x) * 4;
    if (i < 1572864) {
        float4 v = *(const float4*)(Wih + i);
        ushort4 r; r.x = f2bf(v.x); r.y = f2bf(v.y); r.z = f2bf(v.z); r.w = f2bf(v.w);
        *(ushort4*)(wihb + i) = r;
    } else {
        int j = i - 1572864;
        float4 v = *(const float4*)(Whh + j);
        ushort4 r; r.x = f2bf(v.x); r.y = f2bf(v.y); r.z = f2bf(v.z); r.w = f2bf(v.w);
        *(ushort4*)(whhb + j) = r;
    }
}

// ---------------- h_e = encoder_h @ W_h.T + b_h  (bf16 out) ----------------
__global__ __launch_bounds__(256) void k_he(const float* __restrict__ A,
                                            const float* __restrict__ W,
                                            const float* __restrict__ bias,
                                            u16* __restrict__ C) {
    __shared__ float As[64][36];
    __shared__ float Bs[64][37];
    const int m0 = blockIdx.y * 64;
    const int n0 = blockIdx.x * 64;
    const int tid = threadIdx.x;
    const int tx = tid & 15, ty = tid >> 4;
    float acc[4][4] = {};
    for (int kk = 0; kk < 512; kk += 32) {
        #pragma unroll
        for (int i = 0; i < 2; ++i) {
            int idx = tid + i * 256;
            int r = idx >> 3, c4 = (idx & 7) << 2;
            float4 va = *(const float4*)(A + (size_t)(m0 + r) * 512 + kk + c4);
            *(float4*)&As[r][c4] = va;
            float4 vb = *(const float4*)(W + (size_t)(n0 + r) * 512 + kk + c4);
            Bs[r][c4 + 0] = vb.x; Bs[r][c4 + 1] = vb.y;
            Bs[r][c4 + 2] = vb.z; Bs[r][c4 + 3] = vb.w;
        }
        __syncthreads();
        #pragma unroll
        for (int k2 = 0; k2 < 32; ++k2) {
            float a[4], b[4];
            #pragma unroll
            for (int i = 0; i < 4; ++i) a[i] = As[ty * 4 + i][k2];
            #pragma unroll
            for (int j = 0; j < 4; ++j) b[j] = Bs[tx * 4 + j][k2];
            #pragma unroll
            for (int i = 0; i < 4; ++i)
                #pragma unroll
                for (int j = 0; j < 4; ++j) acc[i][j] += a[i] * b[j];
        }
        __syncthreads();
    }
    float bj[4];
    #pragma unroll
    for (int j = 0; j < 4; ++j) bj[j] = bias[n0 + tx * 4 + j];
    #pragma unroll
    for (int i = 0; i < 4; ++i) {
        ushort4 r4;
        r4.x = f2bf(acc[i][0] + bj[0]); r4.y = f2bf(acc[i][1] + bj[1]);
        r4.z = f2bf(acc[i][2] + bj[2]); r4.w = f2bf(acc[i][3] + bj[3]);
        *(ushort4*)(C + (size_t)(m0 + ty * 4 + i) * 512 + n0 + tx * 4) = r4;
    }
}

// ==================== persistent cooperative kernel ====================

struct PArgs2 {
    const float* y;
    const float* Wih;
    const float* bih;
    const float* Whh;
    const float* bhh;
    const float* Wsm;
    const float* bs;
    const u16*   heb;
    float* hdb;     // [2][32][512] double buffer
    float* att;     // [32][512]
    float* se;      // [32][512]
    float* pa;      // [32][8][520]
    u32*   cnt;
    float* out_h;
    float* out_att;
};

struct SMemP {
    u16 he[128][520];                 // resident h_e tile (130 KB)
    union {
        struct { float xs[32][132]; } p1;            // x chunk, fp32 (16.9 KB)
        struct { float red[2][8][32]; } p1r;         // gates reduction
        struct {
            float hb[512];
            float part[64][9];
            float seb[512];
            float epart[128][5];
            float pl[128];
            float red2[2];
            float redz[2];
            float mz[2];
            float ctxp[2][512];
        } p2;
    } u;
    float c_l[2][32];                 // persistent cell state (this block's 2 d x 32 b)
};

// ---- lightweight barriers: relaxed polls, scoped fences (NO per-poll buffer_inv) ----
__device__ inline void gbar(u32* sub, u32* root, u32* flag, u32 inst, int tid, int bk) {
    __syncthreads();
    if (tid == 0) {
        __builtin_amdgcn_fence(__ATOMIC_RELEASE, "agent");
        u32 o = __hip_atomic_fetch_add(&sub[bk & 7], 1u, __ATOMIC_RELAXED, __HIP_MEMORY_SCOPE_AGENT);
        if ((o & 31u) == 31u) {
            u32 o2 = __hip_atomic_fetch_add(root, 1u, __ATOMIC_RELAXED, __HIP_MEMORY_SCOPE_AGENT);
            if ((o2 & 7u) == 7u)
                __hip_atomic_fetch_add(flag, 1u, __ATOMIC_RELAXED, __HIP_MEMORY_SCOPE_AGENT);
        }
        while (__hip_atomic_load(flag, __ATOMIC_RELAXED, __HIP_MEMORY_SCOPE_AGENT) < inst)
            __builtin_amdgcn_s_sleep(1);
        __builtin_amdgcn_fence(__ATOMIC_ACQUIRE, "agent");
    }
    __syncthreads();
}

__device__ inline void gbar_group(u32* cnt, u32 inst, int tid) {
    __syncthreads();
    if (tid == 0) {
        __builtin_amdgcn_fence(__ATOMIC_RELEASE, "agent");
        __hip_atomic_fetch_add(cnt, 1u, __ATOMIC_RELAXED, __HIP_MEMORY_SCOPE_AGENT);
        while (__hip_atomic_load(cnt, __ATOMIC_RELAXED, __HIP_MEMORY_SCOPE_AGENT) < inst)
            __builtin_amdgcn_s_sleep(1);
        __builtin_amdgcn_fence(__ATOMIC_ACQUIRE, "agent");
    }
    __syncthreads();
}

__global__ __launch_bounds__(512) void k_persist(PArgs2 a) {
    __shared__ SMemP sm;
    const int bk  = blockIdx.x;       // 0..255
    const int tid = threadIdx.x;      // 0..511

    // roles
    const int b_at = bk >> 3, ch = bk & 7;          // attention: batch, 128-l chunk
    const int p1b = tid & 31;                       // gates: batch
    const int p1r = (tid >> 5) & 7;                 // gates: row index (g*2+dd)
    const int p1kh = tid >> 8;                      // gates: k half
    const int g_ = p1r >> 1, dd_ = p1r & 1;
    const int grow = g_ * 512 + bk * 2 + dd_;       // W row owned (for all 32 b)

    // ---- stage resident h_e tile ----
    {
        const u16* src = a.heb + ((size_t)(b_at * L_ + ch * 128)) * H_;
        #pragma unroll
        for (int i = 0; i < 16; ++i) {
            int s = tid + i * 512;
            int l = s >> 6, v = s & 63;
            *(uint4*)&sm.he[l][v * 8] = *(const uint4*)(src + (size_t)l * H_ + v * 8);
        }
    }
    if (tid < 64) sm.c_l[tid >> 5][tid & 31] = 0.f;

    // ---- persistent W_s slice in VGPRs: row = ch*64 + (tid>>3), k = j*8 + (tid&7) ----
    const int sr = tid >> 3, skq = tid & 7;
    float wreg[64];
    {
        const float* wp = a.Wsm + (size_t)(ch * 64 + sr) * 512 + skq;
        #pragma unroll
        for (int j = 0; j < 64; ++j) wreg[j] = wp[j * 8];
    }

    // ---- LSTM bias preload (tid<64: b=tid&31, dd=tid>>5) ----
    float bihv[4] = {}, bhhv[4] = {};
    if (tid < 64) {
        int ddl = tid >> 5;
        #pragma unroll
        for (int g = 0; g < 4; ++g) {
            int r = g * 512 + bk * 2 + ddl;
            bihv[g] = a.bih[r];
            bhhv[g] = a.bhh[r];
        }
    }
    float bsv = (tid < 64) ? a.bs[ch * 64 + tid] : 0.f;

    __syncthreads();

    u32* subA = a.cnt + 0;  u32* rootA = a.cnt + 8;  u32* flagA = a.cnt + 9;
    u32* subB = a.cnt + 16; u32* rootB = a.cnt + 24; u32* flagB = a.cnt + 25;
    u32* cA = a.cnt + 32 + b_at;
    u32* cB = a.cnt + 64 + b_at;

    for (int t = 0; t < S_; ++t) {
        const float* hr = a.hdb + (size_t)(t & 1) * (B_ * H_);
        float*       hw = a.hdb + (size_t)((t & 1) ^ 1) * (B_ * H_);

        // ================= P1: gates (row-split, full-K) + local LSTM =================
        float acc = 0.f;
        for (int cbi = 0; cbi < 10; ++cbi) {
            const int cb = cbi * 128;
            {   // stage x chunk [32 b][128 k] fp32 -> LDS (one pass, 512 threads)
                const int b_s = tid >> 4, kq = tid & 15;
                const int gk = cb + kq * 8;
                const float* src;
                if (cb < 256)      src = a.y + (size_t)b_s * (S_ * E_) + (size_t)t * E_ + gk;
                else if (cb < 768) src = a.att + b_s * H_ + (gk - 256);
                else               src = hr + b_s * H_ + (gk - 768);
                float4 v0 = *(const float4*)src;
                float4 v1 = *(const float4*)(src + 4);
                *(float4*)&sm.u.p1.xs[b_s][kq * 8]     = v0;
                *(float4*)&sm.u.p1.xs[b_s][kq * 8 + 4] = v1;
            }
            __syncthreads();
            {   // thread (row, b, khalf): 64 MACs; W fp32 from global (wave-broadcast)
                const float* wrow = (cb < 768) ? (a.Wih + (size_t)grow * 768 + cb)
                                               : (a.Whh + (size_t)grow * 512 + (cb - 768));
                const int ko = p1kh * 64;
                const float* xr = &sm.u.p1.xs[p1b][ko];
                const float* wr = wrow + ko;
                #pragma unroll
                for (int j4 = 0; j4 < 16; ++j4) {
                    float4 w4 = *(const float4*)(wr + j4 * 4);
                    float4 x4 = *(const float4*)(xr + j4 * 4);
                    acc += w4.x * x4.x + w4.y * x4.y + w4.z * x4.z + w4.w * x4.w;
                }
            }
            __syncthreads();
        }
        sm.u.p1r.red[p1kh][p1r][p1b] = acc;
        __syncthreads();
        if (tid < 64) {
            const int b = tid & 31, ddl = tid >> 5;
            float gv[4];
            #pragma unroll
            for (int g = 0; g < 4; ++g)
                gv[g] = sm.u.p1r.red[0][g * 2 + ddl][b] + sm.u.p1r.red[1][g * 2 + ddl][b]
                      + bihv[g] + bhhv[g];
            float si = 1.f / (1.f + expf(-gv[0]));
            float sf = 1.f / (1.f + expf(-gv[1]));
            float so = 1.f / (1.f + expf(-gv[3]));
            float cc = sf * sm.c_l[ddl][b] + si * tanhf(gv[2]);
            float hh = so * tanhf(cc);
            sm.c_l[ddl][b] = cc;
            const int d = bk * 2 + ddl;
            hw[b * H_ + d] = hh;
            a.out_h[(size_t)b * (S_ * H_) + (size_t)t * H_ + d] = hh;
        }

        gbar(subA, rootA, flagA, (u32)(t + 1), tid, bk);   // h_t visible grid-wide

        // ================= P2a: s_e slice (W_s in VGPRs) =================
        sm.u.p2.hb[tid] = hw[b_at * H_ + tid];
        __syncthreads();
        {
            float dp = 0.f;
            #pragma unroll
            for (int j = 0; j < 64; ++j) dp += wreg[j] * sm.u.p2.hb[j * 8 + skq];
            sm.u.p2.part[sr][skq] = dp;
        }
        __syncthreads();
        if (tid < 64) {
            float v = bsv;
            #pragma unroll
            for (int q = 0; q < 8; ++q) v += sm.u.p2.part[tid][q];
            a.se[b_at * H_ + ch * 64 + tid] = v;
        }

        gbar_group(cA, (u32)(8 * (t + 1)), tid);           // se[b] complete

        // ================= P2b: e-dots + softmax partial + ctx (h_e in LDS) =========
        sm.u.p2.seb[tid] = a.se[b_at * H_ + tid];
        __syncthreads();
        {
            const int l = tid & 127, kq4 = tid >> 7;
            const u16*   hrw = &sm.he[l][kq4 * 128];
            const float* sb  = &sm.u.p2.seb[kq4 * 128];
            float dp = 0.f;
            #pragma unroll
            for (int j = 0; j < 16; ++j) {
                uint4 q = *(const uint4*)(hrw + j * 8);
                const float* s8 = sb + j * 8;
                dp += s8[0] * bflo(q.x) + s8[1] * bfhi(q.x)
                    + s8[2] * bflo(q.y) + s8[3] * bfhi(q.y)
                    + s8[4] * bflo(q.z) + s8[5] * bfhi(q.z)
                    + s8[6] * bflo(q.w) + s8[7] * bfhi(q.w);
            }
            sm.u.p2.epart[l][kq4] = dp;
        }
        __syncthreads();
        float ee = 0.f;
        if (tid < 128) {
            ee = sm.u.p2.epart[tid][0] + sm.u.p2.epart[tid][1]
               + sm.u.p2.epart[tid][2] + sm.u.p2.epart[tid][3];
            float m = ee;
            #pragma unroll
            for (int off = 1; off < 64; off <<= 1) m = fmaxf(m, __shfl_xor(m, off));
            if ((tid & 63) == 0) sm.u.p2.red2[tid >> 6] = m;
        }
        __syncthreads();
        if (tid < 128) {
            float m = fmaxf(sm.u.p2.red2[0], sm.u.p2.red2[1]);
            float p = __expf(ee - m);
            sm.u.p2.pl[tid] = p;
            float Z = p;
            #pragma unroll
            for (int off = 1; off < 64; off <<= 1) Z += __shfl_xor(Z, off);
            if ((tid & 63) == 0) sm.u.p2.redz[tid >> 6] = Z;
            if (tid == 0) sm.u.p2.mz[0] = m;
        }
        __syncthreads();
        {
            const int hp = tid & 255, lh = tid >> 8;
            float a0 = 0.f, a1 = 0.f;
            #pragma unroll 8
            for (int j = 0; j < 64; ++j) {
                const int l = lh * 64 + j;
                u32 q = *(const u32*)&sm.he[l][hp * 2];
                float p = sm.u.p2.pl[l];
                a0 += p * bflo(q); a1 += p * bfhi(q);
            }
            sm.u.p2.ctxp[lh][hp * 2]     = a0;
            sm.u.p2.ctxp[lh][hp * 2 + 1] = a1;
        }
        __syncthreads();
        {
            float* dst = a.pa + ((size_t)b_at * 8 + ch) * 520;
            if (tid < 256) {
                float v0 = sm.u.p2.ctxp[0][tid * 2]     + sm.u.p2.ctxp[1][tid * 2];
                float v1 = sm.u.p2.ctxp[0][tid * 2 + 1] + sm.u.p2.ctxp[1][tid * 2 + 1];
                *(float2*)(dst + tid * 2) = make_float2(v0, v1);
            }
            if (tid == 0) {
                dst[512] = sm.u.p2.mz[0];
                dst[513] = sm.u.p2.redz[0] + sm.u.p2.redz[1];
            }
        }

        gbar_group(cB, (u32)(8 * (t + 1)), tid);           // all 8 pa chunks ready

        // ================= P2c: combine -> att slice =================
        if (tid < 64) {
            const float* pab = a.pa + (size_t)b_at * (8 * 520);
            float mv[8], zv[8];
            float M = -3.4e38f;
            #pragma unroll
            for (int q = 0; q < 8; ++q) {
                mv[q] = pab[q * 520 + 512];
                zv[q] = pab[q * 520 + 513];
                M = fmaxf(M, mv[q]);
            }
            float wv[8], Zt = 0.f;
            #pragma unroll
            for (int q = 0; q < 8; ++q) { wv[q] = __expf(mv[q] - M); Zt += wv[q] * zv[q]; }
            const float inv = 1.f / Zt;
            float av = 0.f;
            #pragma unroll
            for (int q = 0; q < 8; ++q) av += wv[q] * pab[q * 520 + ch * 64 + tid];
            av *= inv;
            a.att[b_at * H_ + ch * 64 + tid] = av;
            a.out_att[(size_t)b_at * (S_ * H_) + (size_t)t * H_ + ch * 64 + tid] = av;
        }

        gbar(subB, rootB, flagB, (u32)(t + 1), tid, bk);   // att visible grid-wide
    }
}

// ==================== legacy fallback kernels (verbatim) ====================

__global__ __launch_bounds__(256) void k_gates(const float* __restrict__ y,
                                               const float* __restrict__ att,
                                               const float* __restrict__ h,
                                               const u16* __restrict__ wihb,
                                               const u16* __restrict__ whhb,
                                               float* __restrict__ pg, int t) {
    __shared__ float xs[32][36];
    __shared__ float Ws[64][36];
    const int tid = threadIdx.x;
    const int r = tid & 63;
    const int b0 = (tid >> 6) * 8;
    const int r0 = blockIdx.x * 64;
    const int kbeg = blockIdx.y * 160;
    float acc[8] = {};
    for (int kk = kbeg; kk < kbeg + 160; kk += 32) {
        {
            int b = tid >> 3, j0 = (tid & 7) << 2;
            float4 v;
            if (kk < 256)      v = *(const float4*)(y + (size_t)b * (S_ * E_) + t * E_ + kk + j0);
            else if (kk < 768) v = *(const float4*)(att + b * H_ + (kk - 256) + j0);
            else               v = *(const float4*)(h + b * H_ + (kk - 768) + j0);
            *(float4*)&xs[b][j0] = v;
        }
        {
            int rr = tid >> 2, c8 = (tid & 3) << 3;
            const u16* wp;
            if (kk < 768) wp = wihb + (size_t)(r0 + rr) * 768 + kk + c8;
            else          wp = whhb + (size_t)(r0 + rr) * 512 + (kk - 768) + c8;
            uint4 q = *(const uint4*)wp;
            Ws[rr][c8 + 0] = bflo(q.x); Ws[rr][c8 + 1] = bfhi(q.x);
            Ws[rr][c8 + 2] = bflo(q.y); Ws[rr][c8 + 3] = bfhi(q.y);
            Ws[rr][c8 + 4] = bflo(q.z); Ws[rr][c8 + 5] = bfhi(q.z);
            Ws[rr][c8 + 6] = bflo(q.w); Ws[rr][c8 + 7] = bfhi(q.w);
        }
        __syncthreads();
        #pragma unroll
        for (int j = 0; j < 32; j += 4) {
            float4 w4 = *(float4*)&Ws[r][j];
            #pragma unroll
            for (int bb = 0; bb < 8; ++bb) {
                float4 x4 = *(float4*)&xs[b0 + bb][j];
                acc[bb] += w4.x * x4.x + w4.y * x4.y + w4.z * x4.z + w4.w * x4.w;
            }
        }
        __syncthreads();
    }
    #pragma unroll
    for (int bb = 0; bb < 8; ++bb)
        pg[(size_t)blockIdx.y * (B_ * G4) + (b0 + bb) * G4 + r0 + r] = acc[bb];
}

__global__ void k_lstm(const float* __restrict__ pg,
                       const float* __restrict__ bih, const float* __restrict__ bhh,
                       float* __restrict__ c, float* __restrict__ h,
                       float* __restrict__ out_h, int t) {
    int idx = blockIdx.x * blockDim.x + threadIdx.x;
    int b = idx >> 9, d = idx & 511;
    float gi = bih[d] + bhh[d];
    float gf = bih[512 + d] + bhh[512 + d];
    float gg = bih[1024 + d] + bhh[1024 + d];
    float go = bih[1536 + d] + bhh[1536 + d];
    #pragma unroll
    for (int s = 0; s < 8; ++s) {
        const float* p = pg + (size_t)s * (B_ * G4) + b * G4;
        gi += p[d]; gf += p[512 + d]; gg += p[1024 + d]; go += p[1536 + d];
    }
    float si = 1.f / (1.f + expf(-gi));
    float sf = 1.f / (1.f + expf(-gf));
    float so = 1.f / (1.f + expf(-go));
    float cc = sf * c[idx] + si * tanhf(gg);
    float hh = so * tanhf(cc);
    c[idx] = cc;
    h[idx] = hh;
    out_h[(size_t)b * (S_ * H_) + t * H_ + d] = hh;
}

__global__ __launch_bounds__(256) void k_se(const float* __restrict__ h,
                                            const float* __restrict__ Ws_,
                                            float* __restrict__ pse) {
    __shared__ float xs[32][36];
    __shared__ float Ws[64][36];
    const int tid = threadIdx.x;
    const int r = tid & 63;
    const int b0 = (tid >> 6) * 8;
    const int r0 = blockIdx.x * 64;
    const int kbeg = blockIdx.y * 128;
    float acc[8] = {};
    for (int kk = kbeg; kk < kbeg + 128; kk += 32) {
        {
            int b = tid >> 3, j0 = (tid & 7) << 2;
            *(float4*)&xs[b][j0] = *(const float4*)(h + b * H_ + kk + j0);
        }
        #pragma unroll
        for (int i = 0; i < 2; ++i) {
            int idx = tid + i * 256;
            int rr = idx >> 3, c4 = (idx & 7) << 2;
            *(float4*)&Ws[rr][c4] = *(const float4*)(Ws_ + (size_t)(r0 + rr) * 512 + kk + c4);
        }
        __syncthreads();
        #pragma unroll
        for (int j = 0; j < 32; j += 4) {
            float4 w4 = *(float4*)&Ws[r][j];
            #pragma unroll
            for (int bb = 0; bb < 8; ++bb) {
                float4 x4 = *(float4*)&xs[b0 + bb][j];
                acc[bb] += w4.x * x4.x + w4.y * x4.y + w4.z * x4.z + w4.w * x4.w;
            }
        }
        __syncthreads();
    }
    #pragma unroll
    for (int bb = 0; bb < 8; ++bb)
        pse[(size_t)blockIdx.y * (B_ * H_) + (b0 + bb) * H_ + r0 + r] = acc[bb];
}

__global__ __launch_bounds__(256) void k_attn(const float* __restrict__ pse,
                                              const float* __restrict__ bs,
                                              const u16* __restrict__ he,
                                              float* __restrict__ pa) {
    __shared__ float se[512];
    __shared__ float part[64][5];
    __shared__ float pl[64];
    __shared__ float mz[2];
    const int b = blockIdx.y;
    const int l0 = blockIdx.x * 64;
    const int t = threadIdx.x;
    #pragma unroll
    for (int i = 0; i < 2; ++i) {
        int hh = t + i * 256;
        float v = bs[hh];
        #pragma unroll
        for (int s = 0; s < 4; ++s) v += pse[(size_t)s * (B_ * H_) + b * H_ + hh];
        se[hh] = v;
    }
    __syncthreads();
    const int l = t & 63, w = t >> 6;
    const u16* hrow = he + ((size_t)b * L_ + l0 + l) * H_ + w * 128;
    const float* sew = &se[w * 128];
    float dp = 0.f;
    #pragma unroll
    for (int kc = 0; kc < 128; kc += 8) {
        uint4 q = *(const uint4*)(hrow + kc);
        dp += sew[kc + 0] * bflo(q.x) + sew[kc + 1] * bfhi(q.x)
            + sew[kc + 2] * bflo(q.y) + sew[kc + 3] * bfhi(q.y)
            + sew[kc + 4] * bflo(q.z) + sew[kc + 5] * bfhi(q.z)
            + sew[kc + 6] * bflo(q.w) + sew[kc + 7] * bfhi(q.w);
    }
    part[l][w] = dp;
    __syncthreads();
    if (t < 64) {
        float e = part[t][0] + part[t][1] + part[t][2] + part[t][3];
        float m = e;
        #pragma unroll
        for (int off = 1; off < 64; off <<= 1) m = fmaxf(m, __shfl_xor(m, off));
        float p = __expf(e - m);
        float Z = p;
        #pragma unroll
        for (int off = 1; off < 64; off <<= 1) Z += __shfl_xor(Z, off);
        pl[t] = p;
        if (t == 0) { mz[0] = m; mz[1] = Z; }
    }
    __syncthreads();
    float a0 = 0.f, a1 = 0.f;
    const u16* base2 = he + ((size_t)b * L_ + l0) * H_ + t * 2;
    #pragma unroll 4
    for (int j = 0; j < 64; ++j) {
        u32 q = *(const u32*)(base2 + (size_t)j * H_);
        float p = pl[j];
        a0 += p * bflo(q); a1 += p * bfhi(q);
    }
    float* dst = pa + ((size_t)b * 16 + blockIdx.x) * 520;
    dst[t * 2] = a0; dst[t * 2 + 1] = a1;
    if (t == 0) { dst[512] = mz[0]; dst[513] = mz[1]; }
}

__global__ __launch_bounds__(256) void k_comb(const float* __restrict__ pa,
                                              float* __restrict__ att,
                                              float* __restrict__ out_att, int t) {
    __shared__ float sm[16], sz[16], swt[16], sZt;
    const int b = blockIdx.x;
    const int tid = threadIdx.x;
    if (tid < 16) {
        sm[tid] = pa[((size_t)b * 16 + tid) * 520 + 512];
        sz[tid] = pa[((size_t)b * 16 + tid) * 520 + 513];
    }
    __syncthreads();
    if (tid == 0) {
        float M = sm[0];
        #pragma unroll
        for (int i = 1; i < 16; ++i) M = fmaxf(M, sm[i]);
        float Zt = 0.f;
        #pragma unroll
        for (int i = 0; i < 16; ++i) { float wv = __expf(sm[i] - M); swt[i] = wv; Zt += wv * sz[i]; }
        sZt = Zt;
    }
    __syncthreads();
    const float inv = 1.f / sZt;
    float a0 = 0.f, a1 = 0.f;
    #pragma unroll
    for (int i = 0; i < 16; ++i) {
        const float* p = pa + ((size_t)b * 16 + i) * 520 + tid * 2;
        float wv = swt[i];
        a0 += wv * p[0]; a1 += wv * p[1];
    }
    a0 *= inv; a1 *= inv;
    att[b * H_ + tid * 2] = a0;
    att[b * H_ + tid * 2 + 1] = a1;
    out_att[(size_t)b * (S_ * H_) + t * H_ + tid * 2] = a0;
    out_att[(size_t)b * (S_ * H_) + t * H_ + tid * 2 + 1] = a1;
}

extern "C" void kernel_launch(void* const* d_in, const int* in_sizes, int n_in,
                              void* d_out, int out_size, void* d_ws, size_t ws_size,
                              hipStream_t stream) {
    const float* y   = (const float*)d_in[0];
    const float* enc = (const float*)d_in[1];
    const float* Wih = (const float*)d_in[2];
    const float* bih = (const float*)d_in[3];
    const float* Whh = (const float*)d_in[4];
    const float* bhh = (const float*)d_in[5];
    const float* Ws_ = (const float*)d_in[6];
    const float* bs  = (const float*)d_in[7];
    const float* Wh  = (const float*)d_in[8];
    const float* bh  = (const float*)d_in[9];

    float* ws    = (float*)d_ws;
    u16*   heb   = (u16*)(ws + OFF_HEB);
    u16*   wihb  = (u16*)(ws + OFF_WIHB);
    u16*   whhb  = (u16*)(ws + OFF_WHHB);
    float* hdb   = ws + OFF_H;      // [2][32][512]
    float* att   = ws + OFF_ATT;
    u32*   cnt   = (u32*)(ws + OFF_CNT);
    float* out_h   = (float*)d_out;
    float* out_att = out_h + (size_t)B_ * S_ * H_;

    // zero h double-buffer, att, counters (contiguous region)
    k_zero<<<(3 * B_ * H_ + 128 + 255) / 256, 256, 0, stream>>>(hdb, 3 * B_ * H_ + 128);
    k_he<<<dim3(H_ / 64, (B_ * L_) / 64), 256, 0, stream>>>(enc, Wh, bh, heb);

    PArgs2 pargs;
    pargs.y = y; pargs.Wih = Wih; pargs.bih = bih; pargs.Whh = Whh; pargs.bhh = bhh;
    pargs.Wsm = Ws_; pargs.bs = bs; pargs.heb = heb;
    pargs.hdb = hdb; pargs.att = att;
    pargs.se = ws + OFF_SE2; pargs.pa = ws + OFF_PA2;
    pargs.cnt = cnt; pargs.out_h = out_h; pargs.out_att = out_att;
    void* kp[] = { (void*)&pargs };
    hipError_t err = hipLaunchCooperativeKernel(reinterpret_cast<void*>(k_persist),
                                                dim3(256), dim3(512), kp, 0, stream);
    if (err != hipSuccess) {
        // fallback: legacy 5-kernel per-step loop (uses bf16 weights)
        float* h   = ws + OFF_H;
        float* c   = ws + OFF_C;
        float* pg  = ws + OFF_PGL;
        float* pse = ws + OFF_PSEL;
        float* pa  = ws + OFF_PAL;
        k_cvtw<<<(1572864 + 1048576) / 4 / 256, 256, 0, stream>>>(Wih, Whh, wihb, whhb);
        for (int t = 0; t < S_; ++t) {
            k_gates<<<dim3(32, 8), 256, 0, stream>>>(y, att, h, wihb, whhb, pg, t);
            k_lstm<<<(B_ * H_) / 256, 256, 0, stream>>>(pg, bih, bhh, c, h, out_h, t);
            k_se<<<dim3(8, 4), 256, 0, stream>>>(h, Ws_, pse);
            k_attn<<<dim3(16, 32), 256, 0, stream>>>(pse, bs, heb, pa);
            k_comb<<<32, 256, 0, stream>>>(pa, att, out_att, t);
        }
    }
}

// Round 4
// 5044.081 us; speedup vs baseline: 6.1570x; 4.1056x over previous
//
#include <hip/hip_runtime.h>
#include <math.h>

typedef unsigned short u16;
typedef unsigned int   u32;

#define B_ 32
#define S_ 256
#define E_ 256
#define H_ 512
#define L_ 1024
#define G4 2048      // 4*H

// ---- workspace layout (in floats) ----
#define OFF_HEB  0                         // he bf16: 16,777,216 u16 = 8,388,608 floats
#define OFF_WTT  8388608                   // coop: k-major packed bf16 W (2048*1280 u16 = 1,310,720 floats)
#define OFF_WIHB 8388608                   // fallback: Wih bf16 (row-major)
#define OFF_WHHB 9175040                   // fallback: Whh bf16 (row-major)
#define OFF_HB   9699328                   // h [32][512] (coop) / h (fallback)
#define OFF_C    9715712                   // c (fallback only)
#define OFF_ATT  9732096                   // att (fallback only)
#define OFF_CNT  9748480                   // 2048 floats; u32 barrier counters (coop)
#define OFF_GB   9750528                   // gates buf [32][2048] = 65,536
#define OFF_SEB  9816064                   // se [32][512] = 16,384
#define OFF_PAB  9832448                   // pa [32][8][520] = 133,120 (end 9,965,568)
// legacy fallback scratch (disjoint execution path)
#define OFF_PGL  9750528
#define OFF_PSEL 10274816
#define OFF_PAL  10340352

__device__ inline u16 f2bf(float x) {
    u32 u = __float_as_uint(x);
    u += 0x7fffu + ((u >> 16) & 1u);
    return (u16)(u >> 16);
}
__device__ inline float bflo(u32 q) { return __uint_as_float(q << 16); }
__device__ inline float bfhi(u32 q) { return __uint_as_float(q & 0xffff0000u); }

// ---- cross-block comm: RMW atomics only (performed at agent coherence point) ----
__device__ inline float ldr(const float* p) {
    u32 v = __hip_atomic_fetch_add((u32*)p, 0u, __ATOMIC_RELAXED, __HIP_MEMORY_SCOPE_AGENT);
    return __uint_as_float(v);
}
__device__ inline void str(float* p, float v) {
    __hip_atomic_exchange((u32*)p, __float_as_uint(v), __ATOMIC_RELAXED, __HIP_MEMORY_SCOPE_AGENT);
}

// ---------------- zero init ----------------
__global__ void k_zero(float* __restrict__ p, int n) {
    int i = blockIdx.x * blockDim.x + threadIdx.x;
    if (i < n) p[i] = 0.f;
}

// ---------------- coop: pack W k-major bf16: wtt[kb][r][8], kb=k/8 ----------------
__global__ __launch_bounds__(256) void k_cvtt(const float* __restrict__ Wih,
                                              const float* __restrict__ Whh,
                                              u16* __restrict__ wtt) {
    int gid = blockIdx.x * 256 + threadIdx.x;      // 0 .. 327,679
    int r = gid & 2047, kb = gid >> 11;            // kb 0..159
    int k0 = kb * 8;
    float w[8];
    if (k0 < 768) {
        #pragma unroll
        for (int j = 0; j < 8; ++j) w[j] = Wih[(size_t)r * 768 + k0 + j];
    } else {
        #pragma unroll
        for (int j = 0; j < 8; ++j) w[j] = Whh[(size_t)r * 512 + (k0 - 768) + j];
    }
    uint4 q;
    q.x = (u32)f2bf(w[0]) | ((u32)f2bf(w[1]) << 16);
    q.y = (u32)f2bf(w[2]) | ((u32)f2bf(w[3]) << 16);
    q.z = (u32)f2bf(w[4]) | ((u32)f2bf(w[5]) << 16);
    q.w = (u32)f2bf(w[6]) | ((u32)f2bf(w[7]) << 16);
    *(uint4*)(wtt + ((size_t)kb * 2048 + r) * 8) = q;
}

// ---------------- fallback-only: convert W_ih, W_hh to bf16 (row-major) ----------------
__global__ void k_cvtw(const float* __restrict__ Wih, const float* __restrict__ Whh,
                       u16* __restrict__ wihb, u16* __restrict__ whhb) {
    int i = (blockIdx.x * 256 + threadIdx.x) * 4;
    if (i < 1572864) {
        float4 v = *(const float4*)(Wih + i);
        ushort4 r; r.x = f2bf(v.x); r.y = f2bf(v.y); r.z = f2bf(v.z); r.w = f2bf(v.w);
        *(ushort4*)(wihb + i) = r;
    } else {
        int j = i - 1572864;
        float4 v = *(const float4*)(Whh + j);
        ushort4 r; r.x = f2bf(v.x); r.y = f2bf(v.y); r.z = f2bf(v.z); r.w = f2bf(v.w);
        *(ushort4*)(whhb + j) = r;
    }
}

// ---------------- h_e = encoder_h @ W_h.T + b_h  (bf16 out) ----------------
__global__ __launch_bounds__(256) void k_he(const float* __restrict__ A,
                                            const float* __restrict__ W,
                                            const float* __restrict__ bias,
                                            u16* __restrict__ C) {
    __shared__ float As[64][36];
    __shared__ float Bs[64][37];
    const int m0 = blockIdx.y * 64;
    const int n0 = blockIdx.x * 64;
    const int tid = threadIdx.x;
    const int tx = tid & 15, ty = tid >> 4;
    float acc[4][4] = {};
    for (int kk = 0; kk < 512; kk += 32) {
        #pragma unroll
        for (int i = 0; i < 2; ++i) {
            int idx = tid + i * 256;
            int r = idx >> 3, c4 = (idx & 7) << 2;
            float4 va = *(const float4*)(A + (size_t)(m0 + r) * 512 + kk + c4);
            *(float4*)&As[r][c4] = va;
            float4 vb = *(const float4*)(W + (size_t)(n0 + r) * 512 + kk + c4);
            Bs[r][c4 + 0] = vb.x; Bs[r][c4 + 1] = vb.y;
            Bs[r][c4 + 2] = vb.z; Bs[r][c4 + 3] = vb.w;
        }
        __syncthreads();
        #pragma unroll
        for (int k2 = 0; k2 < 32; ++k2) {
            float a[4], b[4];
            #pragma unroll
            for (int i = 0; i < 4; ++i) a[i] = As[ty * 4 + i][k2];
            #pragma unroll
            for (int j = 0; j < 4; ++j) b[j] = Bs[tx * 4 + j][k2];
            #pragma unroll
            for (int i = 0; i < 4; ++i)
                #pragma unroll
                for (int j = 0; j < 4; ++j) acc[i][j] += a[i] * b[j];
        }
        __syncthreads();
    }
    float bj[4];
    #pragma unroll
    for (int j = 0; j < 4; ++j) bj[j] = bias[n0 + tx * 4 + j];
    #pragma unroll
    for (int i = 0; i < 4; ++i) {
        ushort4 r4;
        r4.x = f2bf(acc[i][0] + bj[0]); r4.y = f2bf(acc[i][1] + bj[1]);
        r4.z = f2bf(acc[i][2] + bj[2]); r4.w = f2bf(acc[i][3] + bj[3]);
        *(ushort4*)(C + (size_t)(m0 + ty * 4 + i) * 512 + n0 + tx * 4) = r4;
    }
}

// ==================== persistent cooperative kernel (per-batch groups) ====================

struct PArgs3 {
    const float* y;
    const float* bih;
    const float* bhh;
    const float* Wsm;
    const float* bs;
    const u16*   heb;
    const u16*   wtt;
    float* hb;      // [32][512]
    float* gb;      // [32][2048]
    float* se;      // [32][512]
    float* pa;      // [32][8][520]
    u32*   cnt;
    float* out_h;
    float* out_att;
};

struct SMemP {
    u16 he[128][520];                 // resident h_e tile; XOR-swizzled 16B slots
    union {
        struct { float xls[1280]; float gred[2][256]; float maz[16]; } p1;
        struct { float hb[512]; float part[64][9]; } p2a;
        struct { float seb[512]; float epart[128][5]; float pl[128];
                 float red2[2]; float redz[2]; float mz[2]; float ctxp[2][512]; } p2b;
    } u;
    float c_l[64];                    // persistent cell state (this block's 64 d for batch b)
};

// ---- group barrier: 8 blocks, relaxed RMW counter (no fences; ordering via vmcnt drain) ----
__device__ inline void gsync(u32* c, u32 tgt) {
    __syncthreads();   // drains all vmem incl. RMW stores before arrival
    if (threadIdx.x == 0) {
        __hip_atomic_fetch_add(c, 1u, __ATOMIC_RELAXED, __HIP_MEMORY_SCOPE_AGENT);
        while (__hip_atomic_fetch_add(c, 0u, __ATOMIC_RELAXED, __HIP_MEMORY_SCOPE_AGENT) < tgt)
            __builtin_amdgcn_s_sleep(2);
    }
    __syncthreads();
}

__global__ __launch_bounds__(512) void k_persist(PArgs3 a) {
    __shared__ SMemP sm;
    const int bk  = blockIdx.x;       // 0..255
    const int tid = threadIdx.x;      // 0..511
    const int b   = bk >> 3;          // batch
    const int ch  = bk & 7;           // chunk: 128 l's, 256 gate rows, 64 d's

    // ---- stage resident h_e tile (XOR-swizzled 16B slots) ----
    {
        const u16* src = a.heb + ((size_t)(b * L_ + ch * 128)) * H_;
        #pragma unroll
        for (int i = 0; i < 16; ++i) {
            int s = tid + i * 512;
            int l = s >> 6, v = s & 63;
            char* dst = (char*)&sm.he[l][0] + ((v * 16) ^ ((l & 7) << 4));
            *(uint4*)dst = *(const uint4*)(src + (size_t)l * H_ + v * 8);
        }
    }
    if (tid < 64) sm.c_l[tid] = 0.f;

    // ---- persistent W_s slice in VGPRs: row = ch*64 + (tid>>3), k = j*8 + (tid&7) ----
    const int sr = tid >> 3, skq = tid & 7;
    float wreg[64];
    {
        const float* wp = a.Wsm + (size_t)(ch * 64 + sr) * 512 + skq;
        #pragma unroll
        for (int j = 0; j < 64; ++j) wreg[j] = wp[j * 8];
    }

    // ---- LSTM bias preload (tid<64: d = ch*64+tid) ----
    float bsum[4] = {};
    if (tid < 64) {
        const int d = ch * 64 + tid;
        #pragma unroll
        for (int g = 0; g < 4; ++g) bsum[g] = a.bih[g * 512 + d] + a.bhh[g * 512 + d];
    }
    const float bsv = (tid < 64) ? a.bs[ch * 64 + tid] : 0.f;

    __syncthreads();

    u32* c0 = a.cnt + ((b * 4 + 0) << 4);
    u32* c1 = a.cnt + ((b * 4 + 1) << 4);
    u32* c2 = a.cnt + ((b * 4 + 2) << 4);
    u32* c3 = a.cnt + ((b * 4 + 3) << 4);

    const int grow_ = tid & 255;      // gates: row within 256-row slice
    const int kh    = tid >> 8;       // gates: k half (wave-uniform)
    const int gr    = ch * 256 + grow_;

    for (int t = 0; t < S_; ++t) {
        // ================= P1: x assembly (+att combine) + gates + store =================
        if (tid < 64) {
            float4 v = *(const float4*)(a.y + (size_t)b * (S_ * E_) + (size_t)t * E_ + tid * 4);
            *(float4*)&sm.u.p1.xls[tid * 4] = v;
        }
        sm.u.p1.xls[768 + tid] = ldr(a.hb + b * H_ + tid);
        if (t > 0) {
            if (tid < 16)
                sm.u.p1.maz[tid] = ldr(a.pa + ((size_t)b * 8 + (tid >> 1)) * 520 + 512 + (tid & 1));
            __syncthreads();
            float M = -3.4e38f;
            #pragma unroll
            for (int q = 0; q < 8; ++q) M = fmaxf(M, sm.u.p1.maz[q * 2]);
            float wv[8], Zt = 0.f;
            #pragma unroll
            for (int q = 0; q < 8; ++q) {
                wv[q] = __expf(sm.u.p1.maz[q * 2] - M);
                Zt += wv[q] * sm.u.p1.maz[q * 2 + 1];
            }
            const float inv = 1.f / Zt;
            float av = 0.f;
            #pragma unroll
            for (int q = 0; q < 8; ++q)
                av += wv[q] * ldr(a.pa + ((size_t)b * 8 + q) * 520 + tid);
            av *= inv;
            sm.u.p1.xls[256 + tid] = av;
            if (ch == 0)
                a.out_att[(size_t)b * (S_ * H_) + (size_t)(t - 1) * H_ + tid] = av;
        } else {
            sm.u.p1.xls[256 + tid] = 0.f;
        }
        __syncthreads();

        {   // gates: row gr, k in [kh*640, kh*640+640); k-major packed bf16 weights
            float ac0 = 0.f, ac1 = 0.f, ac2 = 0.f, ac3 = 0.f;
            const u16* wb = a.wtt + (size_t)(kh * 80) * 2048 * 8 + (size_t)gr * 8;
            #pragma unroll 4
            for (int j = 0; j < 80; ++j) {
                uint4 q = *(const uint4*)(wb + (size_t)j * 2048 * 8);
                const int k0 = kh * 640 + j * 8;
                float4 xa = *(const float4*)&sm.u.p1.xls[k0];
                float4 xb = *(const float4*)&sm.u.p1.xls[k0 + 4];
                ac0 += bflo(q.x) * xa.x + bfhi(q.x) * xa.y;
                ac1 += bflo(q.y) * xa.z + bfhi(q.y) * xa.w;
                ac2 += bflo(q.z) * xb.x + bfhi(q.z) * xb.y;
                ac3 += bflo(q.w) * xb.z + bfhi(q.w) * xb.w;
            }
            sm.u.p1.gred[kh][grow_] = (ac0 + ac1) + (ac2 + ac3);
        }
        __syncthreads();
        if (tid < 256)
            str(a.gb + (size_t)b * G4 + ch * 256 + tid,
                sm.u.p1.gred[0][tid] + sm.u.p1.gred[1][tid]);

        gsync(c0, 8u * (u32)(t + 1));

        // ================= LSTM pointwise: d in [ch*64, ch*64+64) =================
        if (tid < 64) {
            const int d = ch * 64 + tid;
            float gv[4];
            #pragma unroll
            for (int g = 0; g < 4; ++g)
                gv[g] = ldr(a.gb + (size_t)b * G4 + g * 512 + d) + bsum[g];
            float si = 1.f / (1.f + expf(-gv[0]));
            float sf = 1.f / (1.f + expf(-gv[1]));
            float so = 1.f / (1.f + expf(-gv[3]));
            float cc = sf * sm.c_l[tid] + si * tanhf(gv[2]);
            float hh = so * tanhf(cc);
            sm.c_l[tid] = cc;
            str(a.hb + b * H_ + d, hh);
            a.out_h[(size_t)b * (S_ * H_) + (size_t)t * H_ + d] = hh;
        }

        gsync(c1, 8u * (u32)(t + 1));

        // ================= P2a: s_e slice (W_s in VGPRs) =================
        sm.u.p2a.hb[tid] = ldr(a.hb + b * H_ + tid);
        __syncthreads();
        {
            float dp = 0.f;
            #pragma unroll
            for (int j = 0; j < 64; ++j) dp += wreg[j] * sm.u.p2a.hb[j * 8 + skq];
            sm.u.p2a.part[sr][skq] = dp;
        }
        __syncthreads();
        if (tid < 64) {
            float v = bsv;
            #pragma unroll
            for (int q = 0; q < 8; ++q) v += sm.u.p2a.part[tid][q];
            str(a.se + b * H_ + ch * 64 + tid, v);
        }

        gsync(c2, 8u * (u32)(t + 1));

        // ================= P2b: e-dots + softmax partial + ctx (h_e in LDS) =========
        sm.u.p2b.seb[tid] = ldr(a.se + b * H_ + tid);
        __syncthreads();
        {
            const int l = tid & 127, kq4 = tid >> 7;
            const char* hbase = (const char*)&sm.he[l][0];
            const int hsw = (l & 7) << 4;
            const float* sb = &sm.u.p2b.seb[kq4 * 128];
            float dp = 0.f;
            #pragma unroll
            for (int j = 0; j < 16; ++j) {
                uint4 q = *(const uint4*)(hbase + ((kq4 * 256 + j * 16) ^ hsw));
                const float* s8 = sb + j * 8;
                dp += s8[0] * bflo(q.x) + s8[1] * bfhi(q.x)
                    + s8[2] * bflo(q.y) + s8[3] * bfhi(q.y)
                    + s8[4] * bflo(q.z) + s8[5] * bfhi(q.z)
                    + s8[6] * bflo(q.w) + s8[7] * bfhi(q.w);
            }
            sm.u.p2b.epart[l][kq4] = dp;
        }
        __syncthreads();
        float ee = 0.f;
        if (tid < 128) {
            ee = sm.u.p2b.epart[tid][0] + sm.u.p2b.epart[tid][1]
               + sm.u.p2b.epart[tid][2] + sm.u.p2b.epart[tid][3];
            float m = ee;
            #pragma unroll
            for (int off = 1; off < 64; off <<= 1) m = fmaxf(m, __shfl_xor(m, off));
            if ((tid & 63) == 0) sm.u.p2b.red2[tid >> 6] = m;
        }
        __syncthreads();
        if (tid < 128) {
            float m = fmaxf(sm.u.p2b.red2[0], sm.u.p2b.red2[1]);
            float p = __expf(ee - m);
            sm.u.p2b.pl[tid] = p;
            float Z = p;
            #pragma unroll
            for (int off = 1; off < 64; off <<= 1) Z += __shfl_xor(Z, off);
            if ((tid & 63) == 0) sm.u.p2b.redz[tid >> 6] = Z;
            if (tid == 0) sm.u.p2b.mz[0] = m;
        }
        __syncthreads();
        {
            const int hp = tid & 255, lh = tid >> 8;
            float a0 = 0.f, a1 = 0.f;
            #pragma unroll 8
            for (int j = 0; j < 64; ++j) {
                const int l = lh * 64 + j;
                u32 q = *(const u32*)((const char*)&sm.he[l][0] + ((hp * 4) ^ ((l & 7) << 4)));
                float p = sm.u.p2b.pl[l];
                a0 += p * bflo(q); a1 += p * bfhi(q);
            }
            sm.u.p2b.ctxp[lh][hp * 2]     = a0;
            sm.u.p2b.ctxp[lh][hp * 2 + 1] = a1;
        }
        __syncthreads();
        {
            float* dst = a.pa + ((size_t)b * 8 + ch) * 520;
            if (tid < 256) {
                str(dst + tid * 2,     sm.u.p2b.ctxp[0][tid * 2]     + sm.u.p2b.ctxp[1][tid * 2]);
                str(dst + tid * 2 + 1, sm.u.p2b.ctxp[0][tid * 2 + 1] + sm.u.p2b.ctxp[1][tid * 2 + 1]);
            }
            if (tid == 0) {
                str(dst + 512, sm.u.p2b.mz[0]);
                str(dst + 513, sm.u.p2b.redz[0] + sm.u.p2b.redz[1]);
            }
        }

        gsync(c3, 8u * (u32)(t + 1));
    }

    // final out_att[S-1] from pa(S-1) — ch 0 block, direct per-thread combine
    if (ch == 0) {
        float mv[8], zv[8];
        float M = -3.4e38f;
        #pragma unroll
        for (int q = 0; q < 8; ++q) {
            mv[q] = ldr(a.pa + ((size_t)b * 8 + q) * 520 + 512);
            zv[q] = ldr(a.pa + ((size_t)b * 8 + q) * 520 + 513);
            M = fmaxf(M, mv[q]);
        }
        float wv[8], Zt = 0.f;
        #pragma unroll
        for (int q = 0; q < 8; ++q) { wv[q] = __expf(mv[q] - M); Zt += wv[q] * zv[q]; }
        const float inv = 1.f / Zt;
        float av = 0.f;
        #pragma unroll
        for (int q = 0; q < 8; ++q)
            av += wv[q] * ldr(a.pa + ((size_t)b * 8 + q) * 520 + tid);
        a.out_att[(size_t)b * (S_ * H_) + (size_t)(S_ - 1) * H_ + tid] = av * inv;
    }
}

// ==================== legacy fallback kernels (verbatim) ====================

__global__ __launch_bounds__(256) void k_gates(const float* __restrict__ y,
                                               const float* __restrict__ att,
                                               const float* __restrict__ h,
                                               const u16* __restrict__ wihb,
                                               const u16* __restrict__ whhb,
                                               float* __restrict__ pg, int t) {
    __shared__ float xs[32][36];
    __shared__ float Ws[64][36];
    const int tid = threadIdx.x;
    const int r = tid & 63;
    const int b0 = (tid >> 6) * 8;
    const int r0 = blockIdx.x * 64;
    const int kbeg = blockIdx.y * 160;
    float acc[8] = {};
    for (int kk = kbeg; kk < kbeg + 160; kk += 32) {
        {
            int b = tid >> 3, j0 = (tid & 7) << 2;
            float4 v;
            if (kk < 256)      v = *(const float4*)(y + (size_t)b * (S_ * E_) + t * E_ + kk + j0);
            else if (kk < 768) v = *(const float4*)(att + b * H_ + (kk - 256) + j0);
            else               v = *(const float4*)(h + b * H_ + (kk - 768) + j0);
            *(float4*)&xs[b][j0] = v;
        }
        {
            int rr = tid >> 2, c8 = (tid & 3) << 3;
            const u16* wp;
            if (kk < 768) wp = wihb + (size_t)(r0 + rr) * 768 + kk + c8;
            else          wp = whhb + (size_t)(r0 + rr) * 512 + (kk - 768) + c8;
            uint4 q = *(const uint4*)wp;
            Ws[rr][c8 + 0] = bflo(q.x); Ws[rr][c8 + 1] = bfhi(q.x);
            Ws[rr][c8 + 2] = bflo(q.y); Ws[rr][c8 + 3] = bfhi(q.y);
            Ws[rr][c8 + 4] = bflo(q.z); Ws[rr][c8 + 5] = bfhi(q.z);
            Ws[rr][c8 + 6] = bflo(q.w); Ws[rr][c8 + 7] = bfhi(q.w);
        }
        __syncthreads();
        #pragma unroll
        for (int j = 0; j < 32; j += 4) {
            float4 w4 = *(float4*)&Ws[r][j];
            #pragma unroll
            for (int bb = 0; bb < 8; ++bb) {
                float4 x4 = *(float4*)&xs[b0 + bb][j];
                acc[bb] += w4.x * x4.x + w4.y * x4.y + w4.z * x4.z + w4.w * x4.w;
            }
        }
        __syncthreads();
    }
    #pragma unroll
    for (int bb = 0; bb < 8; ++bb)
        pg[(size_t)blockIdx.y * (B_ * G4) + (b0 + bb) * G4 + r0 + r] = acc[bb];
}

__global__ void k_lstm(const float* __restrict__ pg,
                       const float* __restrict__ bih, const float* __restrict__ bhh,
                       float* __restrict__ c, float* __restrict__ h,
                       float* __restrict__ out_h, int t) {
    int idx = blockIdx.x * blockDim.x + threadIdx.x;
    int b = idx >> 9, d = idx & 511;
    float gi = bih[d] + bhh[d];
    float gf = bih[512 + d] + bhh[512 + d];
    float gg = bih[1024 + d] + bhh[1024 + d];
    float go = bih[1536 + d] + bhh[1536 + d];
    #pragma unroll
    for (int s = 0; s < 8; ++s) {
        const float* p = pg + (size_t)s * (B_ * G4) + b * G4;
        gi += p[d]; gf += p[512 + d]; gg += p[1024 + d]; go += p[1536 + d];
    }
    float si = 1.f / (1.f + expf(-gi));
    float sf = 1.f / (1.f + expf(-gf));
    float so = 1.f / (1.f + expf(-go));
    float cc = sf * c[idx] + si * tanhf(gg);
    float hh = so * tanhf(cc);
    c[idx] = cc;
    h[idx] = hh;
    out_h[(size_t)b * (S_ * H_) + t * H_ + d] = hh;
}

__global__ __launch_bounds__(256) void k_se(const float* __restrict__ h,
                                            const float* __restrict__ Ws_,
                                            float* __restrict__ pse) {
    __shared__ float xs[32][36];
    __shared__ float Ws[64][36];
    const int tid = threadIdx.x;
    const int r = tid & 63;
    const int b0 = (tid >> 6) * 8;
    const int r0 = blockIdx.x * 64;
    const int kbeg = blockIdx.y * 128;
    float acc[8] = {};
    for (int kk = kbeg; kk < kbeg + 128; kk += 32) {
        {
            int b = tid >> 3, j0 = (tid & 7) << 2;
            *(float4*)&xs[b][j0] = *(const float4*)(h + b * H_ + kk + j0);
        }
        #pragma unroll
        for (int i = 0; i < 2; ++i) {
            int idx = tid + i * 256;
            int rr = idx >> 3, c4 = (idx & 7) << 2;
            *(float4*)&Ws[rr][c4] = *(const float4*)(Ws_ + (size_t)(r0 + rr) * 512 + kk + c4);
        }
        __syncthreads();
        #pragma unroll
        for (int j = 0; j < 32; j += 4) {
            float4 w4 = *(float4*)&Ws[r][j];
            #pragma unroll
            for (int bb = 0; bb < 8; ++bb) {
                float4 x4 = *(float4*)&xs[b0 + bb][j];
                acc[bb] += w4.x * x4.x + w4.y * x4.y + w4.z * x4.z + w4.w * x4.w;
            }
        }
        __syncthreads();
    }
    #pragma unroll
    for (int bb = 0; bb < 8; ++bb)
        pse[(size_t)blockIdx.y * (B_ * H_) + (b0 + bb) * H_ + r0 + r] = acc[bb];
}

__global__ __launch_bounds__(256) void k_attn(const float* __restrict__ pse,
                                              const float* __restrict__ bs,
                                              const u16* __restrict__ he,
                                              float* __restrict__ pa) {
    __shared__ float se[512];
    __shared__ float part[64][5];
    __shared__ float pl[64];
    __shared__ float mz[2];
    const int b = blockIdx.y;
    const int l0 = blockIdx.x * 64;
    const int t = threadIdx.x;
    #pragma unroll
    for (int i = 0; i < 2; ++i) {
        int hh = t + i * 256;
        float v = bs[hh];
        #pragma unroll
        for (int s = 0; s < 4; ++s) v += pse[(size_t)s * (B_ * H_) + b * H_ + hh];
        se[hh] = v;
    }
    __syncthreads();
    const int l = t & 63, w = t >> 6;
    const u16* hrow = he + ((size_t)b * L_ + l0 + l) * H_ + w * 128;
    const float* sew = &se[w * 128];
    float dp = 0.f;
    #pragma unroll
    for (int kc = 0; kc < 128; kc += 8) {
        uint4 q = *(const uint4*)(hrow + kc);
        dp += sew[kc + 0] * bflo(q.x) + sew[kc + 1] * bfhi(q.x)
            + sew[kc + 2] * bflo(q.y) + sew[kc + 3] * bfhi(q.y)
            + sew[kc + 4] * bflo(q.z) + sew[kc + 5] * bfhi(q.z)
            + sew[kc + 6] * bflo(q.w) + sew[kc + 7] * bfhi(q.w);
    }
    part[l][w] = dp;
    __syncthreads();
    if (t < 64) {
        float e = part[t][0] + part[t][1] + part[t][2] + part[t][3];
        float m = e;
        #pragma unroll
        for (int off = 1; off < 64; off <<= 1) m = fmaxf(m, __shfl_xor(m, off));
        float p = __expf(e - m);
        float Z = p;
        #pragma unroll
        for (int off = 1; off < 64; off <<= 1) Z += __shfl_xor(Z, off);
        pl[t] = p;
        if (t == 0) { mz[0] = m; mz[1] = Z; }
    }
    __syncthreads();
    float a0 = 0.f, a1 = 0.f;
    const u16* base2 = he + ((size_t)b * L_ + l0) * H_ + t * 2;
    #pragma unroll 4
    for (int j = 0; j < 64; ++j) {
        u32 q = *(const u32*)(base2 + (size_t)j * H_);
        float p = pl[j];
        a0 += p * bflo(q); a1 += p * bfhi(q);
    }
    float* dst = pa + ((size_t)b * 16 + blockIdx.x) * 520;
    dst[t * 2] = a0; dst[t * 2 + 1] = a1;
    if (t == 0) { dst[512] = mz[0]; dst[513] = mz[1]; }
}

__global__ __launch_bounds__(256) void k_comb(const float* __restrict__ pa,
                                              float* __restrict__ att,
                                              float* __restrict__ out_att, int t) {
    __shared__ float sm[16], sz[16], swt[16], sZt;
    const int b = blockIdx.x;
    const int tid = threadIdx.x;
    if (tid < 16) {
        sm[tid] = pa[((size_t)b * 16 + tid) * 520 + 512];
        sz[tid] = pa[((size_t)b * 16 + tid) * 520 + 513];
    }
    __syncthreads();
    if (tid == 0) {
        float M = sm[0];
        #pragma unroll
        for (int i = 1; i < 16; ++i) M = fmaxf(M, sm[i]);
        float Zt = 0.f;
        #pragma unroll
        for (int i = 0; i < 16; ++i) { float wv = __expf(sm[i] - M); swt[i] = wv; Zt += wv * sz[i]; }
        sZt = Zt;
    }
    __syncthreads();
    const float inv = 1.f / sZt;
    float a0 = 0.f, a1 = 0.f;
    #pragma unroll
    for (int i = 0; i < 16; ++i) {
        const float* p = pa + ((size_t)b * 16 + i) * 520 + tid * 2;
        float wv = swt[i];
        a0 += wv * p[0]; a1 += wv * p[1];
    }
    a0 *= inv; a1 *= inv;
    att[b * H_ + tid * 2] = a0;
    att[b * H_ + tid * 2 + 1] = a1;
    out_att[(size_t)b * (S_ * H_) + t * H_ + tid * 2] = a0;
    out_att[(size_t)b * (S_ * H_) + t * H_ + tid * 2 + 1] = a1;
}

extern "C" void kernel_launch(void* const* d_in, const int* in_sizes, int n_in,
                              void* d_out, int out_size, void* d_ws, size_t ws_size,
                              hipStream_t stream) {
    const float* y   = (const float*)d_in[0];
    const float* enc = (const float*)d_in[1];
    const float* Wih = (const float*)d_in[2];
    const float* bih = (const float*)d_in[3];
    const float* Whh = (const float*)d_in[4];
    const float* bhh = (const float*)d_in[5];
    const float* Ws_ = (const float*)d_in[6];
    const float* bs  = (const float*)d_in[7];
    const float* Wh  = (const float*)d_in[8];
    const float* bh  = (const float*)d_in[9];

    float* ws    = (float*)d_ws;
    u16*   heb   = (u16*)(ws + OFF_HEB);
    u16*   wtt   = (u16*)(ws + OFF_WTT);
    u16*   wihb  = (u16*)(ws + OFF_WIHB);
    u16*   whhb  = (u16*)(ws + OFF_WHHB);
    float* out_h   = (float*)d_out;
    float* out_att = out_h + (size_t)B_ * S_ * H_;

    // zero h/c/att (fallback-compat span) + counters: floats 9,699,328..9,750,528
    k_zero<<<(51200 + 255) / 256, 256, 0, stream>>>(ws + OFF_HB, 51200);
    k_he<<<dim3(H_ / 64, (B_ * L_) / 64), 256, 0, stream>>>(enc, Wh, bh, heb);
    k_cvtt<<<1280, 256, 0, stream>>>(Wih, Whh, wtt);

    PArgs3 pargs;
    pargs.y = y; pargs.bih = bih; pargs.bhh = bhh; pargs.Wsm = Ws_; pargs.bs = bs;
    pargs.heb = heb; pargs.wtt = wtt;
    pargs.hb = ws + OFF_HB; pargs.gb = ws + OFF_GB;
    pargs.se = ws + OFF_SEB; pargs.pa = ws + OFF_PAB;
    pargs.cnt = (u32*)(ws + OFF_CNT);
    pargs.out_h = out_h; pargs.out_att = out_att;
    void* kp[] = { (void*)&pargs };
    hipError_t err = hipLaunchCooperativeKernel(reinterpret_cast<void*>(k_persist),
                                                dim3(256), dim3(512), kp, 0, stream);
    if (err != hipSuccess) {
        // fallback: legacy 5-kernel per-step loop (uses row-major bf16 weights)
        float* h   = ws + OFF_HB;
        float* c   = ws + OFF_C;
        float* att = ws + OFF_ATT;
        float* pg  = ws + OFF_PGL;
        float* pse = ws + OFF_PSEL;
        float* pa  = ws + OFF_PAL;
        k_cvtw<<<(1572864 + 1048576) / 4 / 256, 256, 0, stream>>>(Wih, Whh, wihb, whhb);
        for (int t = 0; t < S_; ++t) {
            k_gates<<<dim3(32, 8), 256, 0, stream>>>(y, att, h, wihb, whhb, pg, t);
            k_lstm<<<(B_ * H_) / 256, 256, 0, stream>>>(pg, bih, bhh, c, h, out_h, t);
            k_se<<<dim3(8, 4), 256, 0, stream>>>(h, Ws_, pse);
            k_attn<<<dim3(16, 32), 256, 0, stream>>>(pse, bs, heb, pa);
            k_comb<<<32, 256, 0, stream>>>(pa, att, out_att, t);
        }
    }
}